// Round 3
// baseline (174.198 us; speedup 1.0000x reference)
//
#include <hip/hip_runtime.h>
#include <hip/hip_bf16.h>

// ---------------- problem constants ----------------
#define T_LEN 1048576
#define FL    1024
#define PADL  512
#define HOP   256
#define NFR   4097            // frames per batch
#define NB    8
#define NTOT  32776           // NB*NFR
#define XP2   1049600         // T_LEN + FL (reflect-padded length per batch)
#define M_OUT 1026
#define BM 256
#define BN 128
#define BK 32
#define KT 32                 // FL/BK
#define MT 4                  // 1024 rows in main GEMM
#define NT 256                // 32768 frames in main GEMM
#define NWGM 1024             // MT*NT
#define TAIL_ROWBLKS 129      // ceil(NTOT/256)
#define TAIL_BLKS 137         // 129 row-tail + 8 frame-tail

typedef __bf16 bf16x8 __attribute__((ext_vector_type(8)));
typedef float  f32x4  __attribute__((ext_vector_type(4)));

__device__ __forceinline__ void gload16(const __hip_bfloat16* g, void* l) {
  __builtin_amdgcn_global_load_lds(
      (const __attribute__((address_space(1))) unsigned int*)g,
      (__attribute__((address_space(3))) unsigned int*)l, 16, 0, 0);
}

__device__ __forceinline__ float bf2f(unsigned short h) {
  union { unsigned u; float f; } c; c.u = ((unsigned)h) << 16; return c.f;
}

// ---------------- prep: reflect-pad x, convert to bf16 ----------------
__global__ __launch_bounds__(256) void pad_convert_x(
    const float* __restrict__ x, __hip_bfloat16* __restrict__ xp) {
  int i = blockIdx.x * 256 + threadIdx.x;
  int b = blockIdx.y;
  if (i >= XP2) return;
  int t = i - PADL;
  int idx = (t < 0) ? -t : ((t >= T_LEN) ? (2 * T_LEN - 2 - t) : t);
  xp[(size_t)b * XP2 + i] = __float2bfloat16(x[(size_t)b * T_LEN + idx]);
}

// ---------------- prep: basis rows 0..1023 to bf16 ----------------
__global__ __launch_bounds__(256) void convert_basis(
    const float* __restrict__ basis, __hip_bfloat16* __restrict__ bb) {
  int gid = blockIdx.x * 256 + threadIdx.x;
  if (gid >= 1024 * FL) return;
  bb[gid] = __float2bfloat16(basis[gid]);
}

// ---------------- main GEMM: rows 0..1023 x frames 0..32767 ----------------
// 256x128 tile, BK=32, 3 LDS slots (72 KB -> 2 blocks/CU), 4 waves (2Mx2N),
// per-wave 128x64 via 8x4 16x16x32 MFMA. Counted vmcnt(6), distance-2.
__global__ __launch_bounds__(256, 2) void stft_gemm(
    const __hip_bfloat16* __restrict__ A,   // [1024][FL]
    const __hip_bfloat16* __restrict__ X,   // [NB][XP2]
    float* __restrict__ out) {              // [NB][M_OUT][NFR]
  __shared__ __hip_bfloat16 As[3][BM * BK];   // 3 x 16 KB
  __shared__ __hip_bfloat16 Bs[3][BN * BK];   // 3 x 8 KB

  // XCD swizzle (1024 % 8 == 0 -> simple bijection)
  const int orig = blockIdx.x;
  const int wg = (orig & 7) * (NWGM / 8) + (orig >> 3);
  const int mtile = wg & 3, ntile = wg >> 2;
  const int tileM = mtile * BM, tileN = ntile * BN;

  const int tid = threadIdx.x;
  const int w = tid >> 6, l = tid & 63;      // 4 waves
  const int wm = w >> 1, wn = w & 1;

  // ---- staging addressing (pre-swizzled global source, linear LDS dest) ----
  const int gslot = (l & 3) ^ ((l >> 3) & 3);   // inverse swizzle on source
  const int srow = l >> 2;                       // row within 16-row chunk

  // A: 4 chunks per wave (chunk c = w*4+j covers rows c*16..+15)
  const __hip_bfloat16* aSrc[4];
#pragma unroll
  for (int j = 0; j < 4; ++j) {
    const int c = w * 4 + j;
    aSrc[j] = A + (size_t)(tileM + c * 16 + srow) * FL + gslot * 8;
  }
  // B: 2 chunks per wave (chunk cb = w*2+j covers frames cb*16..+15)
  const __hip_bfloat16* bSrc[2];
#pragma unroll
  for (int j = 0; j < 2; ++j) {
    const int cb = w * 2 + j;
    const int fg = tileN + cb * 16 + srow;       // < 32768 always
    const int bb = fg / NFR;
    const int fb = fg - bb * NFR;
    bSrc[j] = X + (size_t)bb * XP2 + (size_t)fb * HOP + gslot * 8;
  }
  const int aOff0 = (w * 4) * 512;   // elems; chunk j adds j*512
  const int bOff0 = (w * 2) * 512;

  // ---- fragment read addressing (swizzled) ----
  const int swz = (((l >> 4) * 8) ^ ((l & 6) << 2));
  const int aIdx = (wm * 128 + (l & 15)) * BK + swz;
  const int bIdx = (wn * 64 + (l & 15)) * BK + swz;

  f32x4 acc[8][4] = {};

#define STAGE(t_, sl_) do {                                   \
    const int ko_ = (t_) * BK;                                \
    _Pragma("unroll") for (int j = 0; j < 4; ++j)             \
      gload16(aSrc[j] + ko_, (void*)&As[sl_][aOff0 + j*512]); \
    _Pragma("unroll") for (int j = 0; j < 2; ++j)             \
      gload16(bSrc[j] + ko_, (void*)&Bs[sl_][bOff0 + j*512]); \
  } while (0)

#define ITER(t_, sl_, ssl_, VM_, STG_) do {                                 \
    asm volatile("s_waitcnt vmcnt(" #VM_ ")" ::: "memory");                 \
    __builtin_amdgcn_sched_barrier(0);                                      \
    __builtin_amdgcn_s_barrier();                                           \
    if (STG_) STAGE((t_) + 2, ssl_);                                        \
    bf16x8 af[8], bfr[4];                                                   \
    _Pragma("unroll") for (int m = 0; m < 8; ++m)                           \
      af[m] = *(const bf16x8*)&As[sl_][aIdx + m * 512];                     \
    _Pragma("unroll") for (int n = 0; n < 4; ++n)                           \
      bfr[n] = *(const bf16x8*)&Bs[sl_][bIdx + n * 512];                    \
    __builtin_amdgcn_s_setprio(1);                                          \
    _Pragma("unroll") for (int m = 0; m < 8; ++m)                           \
      _Pragma("unroll") for (int n = 0; n < 4; ++n)                         \
        acc[m][n] = __builtin_amdgcn_mfma_f32_16x16x32_bf16(                \
            af[m], bfr[n], acc[m][n], 0, 0, 0);                             \
    __builtin_amdgcn_s_setprio(0);                                          \
  } while (0)

  STAGE(0, 0); STAGE(1, 1);
  for (int tb = 0; tb < KT - 2; tb += 3) {          // tb = 0,3,...,27
    ITER(tb + 0, 0, 2, 6, true);
    ITER(tb + 1, 1, 0, 6, true);
    ITER(tb + 2, 2, 1, 6, true);
  }
  ITER(KT - 2, 0, 2, 6, false);
  ITER(KT - 1, 1, 0, 0, false);

#undef ITER
#undef STAGE

  // ---- epilogue: C/D layout col = lane&15 (frame), row = (lane>>4)*4 + j ----
  const int cn = l & 15, rb = (l >> 4) * 4;
  size_t obase[4];
#pragma unroll
  for (int n = 0; n < 4; ++n) {
    const int fg = tileN + wn * 64 + n * 16 + cn;   // < 32768
    const int bb = fg / NFR;
    const int fb = fg - bb * NFR;
    obase[n] = (size_t)bb * M_OUT * NFR + fb;
  }
#pragma unroll
  for (int m = 0; m < 8; ++m) {
    const int o0 = tileM + wm * 128 + m * 16 + rb;  // < 1024
#pragma unroll
    for (int j = 0; j < 4; ++j) {
      const int o = o0 + j;
#pragma unroll
      for (int n = 0; n < 4; ++n)
        out[obase[n] + (size_t)o * NFR] = acc[m][n][j];
    }
  }
}

// ---------------- tail: rows 1024/1025 (all frames) + last 8 frames ----------------
__global__ __launch_bounds__(256) void stft_tail(
    const float* __restrict__ basis,            // [1026][1024] f32
    const __hip_bfloat16* __restrict__ xp,      // [NB][XP2]
    const __hip_bfloat16* __restrict__ basisBf, // [1024][1024]
    float* __restrict__ out) {
  const int blk = blockIdx.x;
  if (blk < TAIL_ROWBLKS) {
    // rows 1024, 1025 for frames blk*256 + tid
    __shared__ float b0[1024], b1[1024];
    for (int i = threadIdx.x; i < 1024; i += 256) {
      b0[i] = basis[1024 * 1024 + i];
      b1[i] = basis[1025 * 1024 + i];
    }
    __syncthreads();
    const int fg = blk * 256 + threadIdx.x;
    if (fg >= NTOT) return;
    const int b = fg / NFR, fb = fg - b * NFR;
    const __hip_bfloat16* w = xp + (size_t)b * XP2 + (size_t)fb * HOP;
    float s0 = 0.f, s1 = 0.f;
    for (int k = 0; k < 1024; k += 8) {
      bf16x8 v = *(const bf16x8*)&w[k];
      union { bf16x8 v8; unsigned short u[8]; } uu; uu.v8 = v;
#pragma unroll
      for (int j = 0; j < 8; ++j) {
        const float xv = bf2f(uu.u[j]);
        s0 += b0[k + j] * xv;
        s1 += b1[k + j] * xv;
      }
    }
    out[((size_t)b * M_OUT + 1024) * NFR + fb] = s0;
    out[((size_t)b * M_OUT + 1025) * NFR + fb] = s1;
  } else {
    // frames 32768..32775 (batch 7), rows 0..1023
    const int fg = 32768 + (blk - TAIL_ROWBLKS);
    const int b = 7, fb = fg - 7 * NFR;
    __shared__ __hip_bfloat16 win[1024];
    const __hip_bfloat16* w = xp + (size_t)b * XP2 + (size_t)fb * HOP;
    for (int i = threadIdx.x; i < 1024; i += 256) win[i] = w[i];
    __syncthreads();
#pragma unroll
    for (int rr = 0; rr < 4; ++rr) {
      const int r = threadIdx.x * 4 + rr;
      const __hip_bfloat16* br = basisBf + (size_t)r * FL;
      float s = 0.f;
      for (int k = 0; k < 1024; k += 8) {
        union { bf16x8 v8; unsigned short u[8]; } ub, ux;
        ub.v8 = *(const bf16x8*)&br[k];
        ux.v8 = *(const bf16x8*)&win[k];
#pragma unroll
        for (int j = 0; j < 8; ++j) s += bf2f(ub.u[j]) * bf2f(ux.u[j]);
      }
      out[((size_t)b * M_OUT + r) * NFR + fb] = s;
    }
  }
}

extern "C" void kernel_launch(void* const* d_in, const int* in_sizes, int n_in,
                              void* d_out, int out_size, void* d_ws, size_t ws_size,
                              hipStream_t stream) {
  const float* x = (const float*)d_in[0];       // [8, 1048576] f32
  const float* basis = (const float*)d_in[1];   // [1026, 1, 1024] f32
  float* out = (float*)d_out;                   // [8, 1026, 4097] f32

  __hip_bfloat16* xpBf = (__hip_bfloat16*)d_ws;                 // NB*XP2 bf16
  __hip_bfloat16* basisBf = xpBf + (size_t)NB * XP2;            // 1024*FL bf16

  dim3 gPad((XP2 + 255) / 256, NB);
  pad_convert_x<<<gPad, 256, 0, stream>>>(x, xpBf);

  dim3 gBas((1024 * FL + 255) / 256);
  convert_basis<<<gBas, 256, 0, stream>>>(basis, basisBf);

  stft_gemm<<<NWGM, 256, 0, stream>>>(basisBf, xpBf, out);
  stft_tail<<<TAIL_BLKS, 256, 0, stream>>>(basis, xpBf, basisBf, out);
}

// Round 4
// 136.418 us; speedup vs baseline: 1.2769x; 1.2769x over previous
//
#include <hip/hip_runtime.h>
#include <hip/hip_bf16.h>

// ---------------- problem constants ----------------
#define T_LEN 1048576
#define FL    1024
#define PADL  512
#define HOP   256
#define NFR   4097            // frames per batch
#define NB    8
#define NTOT  32776           // NB*NFR
#define XP2   1049600         // T_LEN + FL (reflect-padded length per batch)
#define M_OUT 1026
#define BM 256
#define BN 128
#define BK 32
#define KT 32                 // FL/BK
#define MT 4                  // 1024 rows in main GEMM
#define NT 257                // 32896 frames covered (incl. 8-frame tail)
#define NWGM 1028             // MT*NT
#define TAIL2_BLKS 1025       // ceil(NTOT/32)

typedef __bf16 bf16x8 __attribute__((ext_vector_type(8)));
typedef float  f32x4  __attribute__((ext_vector_type(4)));

__device__ __forceinline__ void gload16(const __hip_bfloat16* g, void* l) {
  __builtin_amdgcn_global_load_lds(
      (const __attribute__((address_space(1))) unsigned int*)g,
      (__attribute__((address_space(3))) unsigned int*)l, 16, 0, 0);
}

__device__ __forceinline__ float bf2f(unsigned short h) {
  union { unsigned u; float f; } c; c.u = ((unsigned)h) << 16; return c.f;
}

// ---------------- prep: reflect-pad x, convert to bf16 ----------------
__global__ __launch_bounds__(256) void pad_convert_x(
    const float* __restrict__ x, __hip_bfloat16* __restrict__ xp) {
  int i = blockIdx.x * 256 + threadIdx.x;
  int b = blockIdx.y;
  if (i >= XP2) return;
  int t = i - PADL;
  int idx = (t < 0) ? -t : ((t >= T_LEN) ? (2 * T_LEN - 2 - t) : t);
  xp[(size_t)b * XP2 + i] = __float2bfloat16(x[(size_t)b * T_LEN + idx]);
}

// ---------------- prep: basis rows 0..1023 to bf16 ----------------
__global__ __launch_bounds__(256) void convert_basis(
    const float* __restrict__ basis, __hip_bfloat16* __restrict__ bb) {
  int gid = blockIdx.x * 256 + threadIdx.x;
  if (gid >= 1024 * FL) return;
  bb[gid] = __float2bfloat16(basis[gid]);
}

// ---------------- main GEMM: rows 0..1023 x frames 0..32895 (stores <32776) ----------------
// 256x128 tile, BK=32, 3 LDS slots (72 KB -> 2 blocks/CU), 4 waves (2Mx2N),
// per-wave 128x64 via 8x4 16x16x32 MFMA. Counted vmcnt(6), distance-2.
__global__ __launch_bounds__(256, 2) void stft_gemm(
    const __hip_bfloat16* __restrict__ A,   // [1024][FL]
    const __hip_bfloat16* __restrict__ X,   // [NB][XP2]
    float* __restrict__ out) {              // [NB][M_OUT][NFR]
  __shared__ __hip_bfloat16 As[3][BM * BK];   // 3 x 16 KB
  __shared__ __hip_bfloat16 Bs[3][BN * BK];   // 3 x 8 KB

  // bijective XCD swizzle (NWGM % 8 == 4)
  const int orig = blockIdx.x;
  const int xcd = orig & 7, lin = orig >> 3;
  const int qq = NWGM >> 3, rr = NWGM & 7;
  const int wg = (xcd < rr ? xcd * (qq + 1) : rr * (qq + 1) + (xcd - rr) * qq) + lin;
  const int mtile = wg & 3, ntile = wg >> 2;
  const int tileM = mtile * BM, tileN = ntile * BN;

  const int tid = threadIdx.x;
  const int w = tid >> 6, l = tid & 63;      // 4 waves
  const int wm = w >> 1, wn = w & 1;

  // ---- staging addressing (pre-swizzled global source, linear LDS dest) ----
  const int gslot = (l & 3) ^ ((l >> 3) & 3);   // inverse swizzle on source
  const int srow = l >> 2;                       // row within 16-row chunk

  // A: 4 chunks per wave (chunk c = w*4+j covers rows c*16..+15)
  const __hip_bfloat16* aSrc[4];
#pragma unroll
  for (int j = 0; j < 4; ++j) {
    const int c = w * 4 + j;
    aSrc[j] = A + (size_t)(tileM + c * 16 + srow) * FL + gslot * 8;
  }
  // B: 2 chunks per wave (chunk cb = w*2+j covers frames cb*16..+15)
  const __hip_bfloat16* bSrc[2];
#pragma unroll
  for (int j = 0; j < 2; ++j) {
    const int cb = w * 2 + j;
    int fg = tileN + cb * 16 + srow;
    if (fg > NTOT - 1) fg = NTOT - 1;            // clamp (outputs discarded)
    const int bb = fg / NFR;
    const int fb = fg - bb * NFR;
    bSrc[j] = X + (size_t)bb * XP2 + (size_t)fb * HOP + gslot * 8;
  }
  const int aOff0 = (w * 4) * 512;   // elems; chunk j adds j*512
  const int bOff0 = (w * 2) * 512;

  // ---- fragment read addressing (swizzled) ----
  const int swz = (((l >> 4) * 8) ^ ((l & 6) << 2));
  const int aIdx = (wm * 128 + (l & 15)) * BK + swz;
  const int bIdx = (wn * 64 + (l & 15)) * BK + swz;

  f32x4 acc[8][4] = {};

#define STAGE(t_, sl_) do {                                   \
    const int ko_ = (t_) * BK;                                \
    _Pragma("unroll") for (int j = 0; j < 4; ++j)             \
      gload16(aSrc[j] + ko_, (void*)&As[sl_][aOff0 + j*512]); \
    _Pragma("unroll") for (int j = 0; j < 2; ++j)             \
      gload16(bSrc[j] + ko_, (void*)&Bs[sl_][bOff0 + j*512]); \
  } while (0)

#define ITER(t_, sl_, ssl_, VM_, STG_) do {                                 \
    asm volatile("s_waitcnt vmcnt(" #VM_ ")" ::: "memory");                 \
    __builtin_amdgcn_sched_barrier(0);                                      \
    __builtin_amdgcn_s_barrier();                                           \
    if (STG_) STAGE((t_) + 2, ssl_);                                        \
    bf16x8 af[8], bfr[4];                                                   \
    _Pragma("unroll") for (int m = 0; m < 8; ++m)                           \
      af[m] = *(const bf16x8*)&As[sl_][aIdx + m * 512];                     \
    _Pragma("unroll") for (int n = 0; n < 4; ++n)                           \
      bfr[n] = *(const bf16x8*)&Bs[sl_][bIdx + n * 512];                    \
    __builtin_amdgcn_s_setprio(1);                                          \
    _Pragma("unroll") for (int m = 0; m < 8; ++m)                           \
      _Pragma("unroll") for (int n = 0; n < 4; ++n)                         \
        acc[m][n] = __builtin_amdgcn_mfma_f32_16x16x32_bf16(                \
            af[m], bfr[n], acc[m][n], 0, 0, 0);                             \
    __builtin_amdgcn_s_setprio(0);                                          \
  } while (0)

  STAGE(0, 0); STAGE(1, 1);
  for (int tb = 0; tb < KT - 2; tb += 3) {          // tb = 0,3,...,27
    ITER(tb + 0, 0, 2, 6, true);
    ITER(tb + 1, 1, 0, 6, true);
    ITER(tb + 2, 2, 1, 6, true);
  }
  ITER(KT - 2, 0, 2, 6, false);
  ITER(KT - 1, 1, 0, 0, false);

#undef ITER
#undef STAGE

  // ---- epilogue: C/D layout col = lane&15 (frame), row = (lane>>4)*4 + j ----
  const int cn = l & 15, rb = (l >> 4) * 4;
  size_t obase[4];
  bool vn[4];
#pragma unroll
  for (int n = 0; n < 4; ++n) {
    const int fg = tileN + wn * 64 + n * 16 + cn;
    vn[n] = fg < NTOT;
    const int fgc = vn[n] ? fg : 0;
    const int bb = fgc / NFR;
    const int fb = fgc - bb * NFR;
    obase[n] = (size_t)bb * M_OUT * NFR + fb;
  }
#pragma unroll
  for (int m = 0; m < 8; ++m) {
    const int o0 = tileM + wm * 128 + m * 16 + rb;  // < 1024
#pragma unroll
    for (int j = 0; j < 4; ++j) {
      const int o = o0 + j;
#pragma unroll
      for (int n = 0; n < 4; ++n)
        if (vn[n]) out[obase[n] + (size_t)o * NFR] = acc[m][n][j];
    }
  }
}

// ---------------- tail: rows 1024/1025, all frames. K-split 8 x 32 frames/block ----------------
__global__ __launch_bounds__(256) void stft_tail2(
    const float* __restrict__ basis,            // [1026][1024] f32
    const __hip_bfloat16* __restrict__ xp,      // [NB][XP2]
    float* __restrict__ out) {
  __shared__ float b0[1024], b1[1024];
  __shared__ float part[2][8][32];
  for (int i = threadIdx.x; i < 1024; i += 256) {
    b0[i] = basis[1024 * 1024 + i];
    b1[i] = basis[1025 * 1024 + i];
  }
  __syncthreads();
  const int fl = threadIdx.x & 31, ks = threadIdx.x >> 5;  // 32 frames x 8 K-segs
  const int fg = blockIdx.x * 32 + fl;
  float s0 = 0.f, s1 = 0.f;
  if (fg < NTOT) {
    const int b = fg / NFR, fb = fg - b * NFR;
    const __hip_bfloat16* w = xp + (size_t)b * XP2 + (size_t)fb * HOP + ks * 128;
    const float* bb0 = b0 + ks * 128;
    const float* bb1 = b1 + ks * 128;
#pragma unroll 4
    for (int k = 0; k < 128; k += 8) {
      union { bf16x8 v; unsigned short u[8]; } uu;
      uu.v = *(const bf16x8*)&w[k];
#pragma unroll
      for (int j = 0; j < 8; ++j) {
        const float xv = bf2f(uu.u[j]);
        s0 += bb0[k + j] * xv;
        s1 += bb1[k + j] * xv;
      }
    }
  }
  part[0][ks][fl] = s0;
  part[1][ks][fl] = s1;
  __syncthreads();
  if (threadIdx.x < 64) {
    const int row = threadIdx.x >> 5, f = threadIdx.x & 31;
    const int fg2 = blockIdx.x * 32 + f;
    if (fg2 < NTOT) {
      float s = 0.f;
#pragma unroll
      for (int k2 = 0; k2 < 8; ++k2) s += part[row][k2][f];
      const int b = fg2 / NFR, fb = fg2 - b * NFR;
      out[((size_t)b * M_OUT + 1024 + row) * NFR + fb] = s;
    }
  }
}

extern "C" void kernel_launch(void* const* d_in, const int* in_sizes, int n_in,
                              void* d_out, int out_size, void* d_ws, size_t ws_size,
                              hipStream_t stream) {
  const float* x = (const float*)d_in[0];       // [8, 1048576] f32
  const float* basis = (const float*)d_in[1];   // [1026, 1, 1024] f32
  float* out = (float*)d_out;                   // [8, 1026, 4097] f32

  __hip_bfloat16* xpBf = (__hip_bfloat16*)d_ws;                 // NB*XP2 bf16
  __hip_bfloat16* basisBf = xpBf + (size_t)NB * XP2;            // 1024*FL bf16

  dim3 gPad((XP2 + 255) / 256, NB);
  pad_convert_x<<<gPad, 256, 0, stream>>>(x, xpBf);

  dim3 gBas((1024 * FL + 255) / 256);
  convert_basis<<<gBas, 256, 0, stream>>>(basis, basisBf);

  stft_gemm<<<NWGM, 256, 0, stream>>>(basisBf, xpBf, out);
  stft_tail2<<<TAIL2_BLKS, 256, 0, stream>>>(basis, xpBf, out);
}

// Round 5
// 111.176 us; speedup vs baseline: 1.5669x; 1.2270x over previous
//
#include <hip/hip_runtime.h>
#include <hip/hip_bf16.h>

// ---------------- problem constants ----------------
#define T_LEN 1048576
#define FL    1024
#define PADL  512
#define HOP   256
#define NFR   4097            // frames per batch
#define NB    8
#define NTOT  32776           // NB*NFR
#define XP2   1049600         // T_LEN + FL (reflect-padded length per batch)
#define M_OUT 1026
#define BM 256
#define BN 256
#define BK 64
#define KT8 16                // FL/BK
#define MT 4                  // 1024 rows
#define NT 128                // 32768 frames in main GEMM
#define NWGM 512              // MT*NT -> exactly 2 rounds at 1 block/CU
#define TAIL_ROW 1025         // ceil(NTOT/32)
#define TAIL_BLKS 1089        // + 64 frame-tail blocks

typedef __bf16 bf16x8 __attribute__((ext_vector_type(8)));
typedef float  f32x4  __attribute__((ext_vector_type(4)));

__device__ __forceinline__ void gload16(const __hip_bfloat16* g, void* l) {
  __builtin_amdgcn_global_load_lds(
      (const __attribute__((address_space(1))) unsigned int*)g,
      (__attribute__((address_space(3))) unsigned int*)l, 16, 0, 0);
}

__device__ __forceinline__ float bf2f(unsigned short h) {
  union { unsigned u; float f; } c; c.u = ((unsigned)h) << 16; return c.f;
}

// ---------------- prep: reflect-pad x, convert to bf16 (8 elems/thread) ----------------
__global__ __launch_bounds__(256) void pad_convert_x8(
    const float* __restrict__ x, __hip_bfloat16* __restrict__ xp) {
  const int base = (blockIdx.x * 256 + threadIdx.x) * 8;
  const int b = blockIdx.y;
  if (base >= XP2) return;
  const float* __restrict__ xb = x + (size_t)b * T_LEN;
  union { bf16x8 v; __hip_bfloat16 h[8]; } o;
  if (base >= PADL && base + 8 <= PADL + T_LEN) {
    const float4 v0 = *(const float4*)&xb[base - PADL];
    const float4 v1 = *(const float4*)&xb[base - PADL + 4];
    o.h[0] = __float2bfloat16(v0.x); o.h[1] = __float2bfloat16(v0.y);
    o.h[2] = __float2bfloat16(v0.z); o.h[3] = __float2bfloat16(v0.w);
    o.h[4] = __float2bfloat16(v1.x); o.h[5] = __float2bfloat16(v1.y);
    o.h[6] = __float2bfloat16(v1.z); o.h[7] = __float2bfloat16(v1.w);
    *(bf16x8*)&xp[(size_t)b * XP2 + base] = o.v;
  } else {
    for (int e = 0; e < 8; ++e) {
      const int i = base + e;
      if (i < XP2) {
        const int t = i - PADL;
        const int idx = (t < 0) ? -t : ((t >= T_LEN) ? (2 * T_LEN - 2 - t) : t);
        xp[(size_t)b * XP2 + i] = __float2bfloat16(xb[idx]);
      }
    }
  }
}

// ---------------- prep: basis rows 0..1023 to bf16 (8 elems/thread) ----------------
__global__ __launch_bounds__(256) void convert_basis8(
    const float* __restrict__ basis, __hip_bfloat16* __restrict__ bb) {
  const int base = (blockIdx.x * 256 + threadIdx.x) * 8;
  if (base >= 1024 * FL) return;
  const float4 v0 = *(const float4*)&basis[base];
  const float4 v1 = *(const float4*)&basis[base + 4];
  union { bf16x8 v; __hip_bfloat16 h[8]; } o;
  o.h[0] = __float2bfloat16(v0.x); o.h[1] = __float2bfloat16(v0.y);
  o.h[2] = __float2bfloat16(v0.z); o.h[3] = __float2bfloat16(v0.w);
  o.h[4] = __float2bfloat16(v1.x); o.h[5] = __float2bfloat16(v1.y);
  o.h[6] = __float2bfloat16(v1.z); o.h[7] = __float2bfloat16(v1.w);
  *(bf16x8*)&bb[base] = o.v;
}

// ---------------- main GEMM: 8-phase 256x256 schedule ----------------
// BK=64 split into 2 K-halves; per K-tile 4 phases (K-half x m-half),
// 16 MFMA/phase, 1 half-tile stage (2 gloads)/phase, vmcnt(4) at ph1/ph3.
// LDS: 2 dbuf x 2 khalf x [256 rows][32 cols] per matrix = 128 KiB.
__global__ __launch_bounds__(512, 2) void stft_gemm8(
    const __hip_bfloat16* __restrict__ A,   // [1024][FL]
    const __hip_bfloat16* __restrict__ X,   // [NB][XP2]
    float* __restrict__ out) {              // [NB][M_OUT][NFR]
  __shared__ __hip_bfloat16 As[2][2][256 * 32];
  __shared__ __hip_bfloat16 Bs[2][2][256 * 32];

  // XCD swizzle (512 % 8 == 0)
  const int orig = blockIdx.x;
  const int wg = (orig & 7) * (NWGM / 8) + (orig >> 3);
  const int mtile = wg & 3, ntile = wg >> 2;
  const int tileM = mtile * BM, tileN = ntile * BN;

  const int tid = threadIdx.x;
  const int w = tid >> 6, l = tid & 63;     // 8 waves
  const int wm = w >> 2, wn = w & 3;        // 2M x 4N; per-wave 128x64

  // ---- staging addressing ----
  // half-tile (256 rows x 32 cols bf16 = 16KB) = 16 chunks of 16 rows;
  // chunk c = j*8 + w; lane -> row c*16 + (l>>2), phys col group l&3.
  // swizzle: phys_g = logical_g ^ ((row>>1)&3)  ->  logical on source side.
  const int g_log = (l & 3) ^ ((l >> 3) & 3);
  const int srow = l >> 2;
  const __hip_bfloat16* aBase[2];
  const __hip_bfloat16* bBase[2];
#pragma unroll
  for (int j = 0; j < 2; ++j) {
    const int c = j * 8 + w;
    aBase[j] = A + (size_t)(tileM + c * 16 + srow) * FL + g_log * 8;
    const int fg = tileN + c * 16 + srow;            // < 32768
    const int bb = fg / NFR;
    const int fb = fg - bb * NFR;
    bBase[j] = X + (size_t)bb * XP2 + (size_t)fb * HOP + g_log * 8;
  }

  // ---- fragment read addressing (swizzled; 2-way bank alias = free) ----
  const int swz = ((l >> 4) ^ ((l >> 1) & 3)) * 8;
  const int aIdx = (wm * 128 + (l & 15)) * 32 + swz;
  const int bIdx = (wn * 64 + (l & 15)) * 32 + swz;

  f32x4 acc[8][4] = {};
  bf16x8 bfr[4];

#define STAGE(TT_, DBN_, H_) do {                                            \
    const int co_ = (TT_) * 64 + ((H_) >> 1) * 32;                           \
    if ((H_) & 1) {                                                          \
      _Pragma("unroll") for (int j = 0; j < 2; ++j)                          \
        gload16(bBase[j] + co_, (void*)&Bs[DBN_][(H_) >> 1][(j*8 + w)*512]); \
    } else {                                                                 \
      _Pragma("unroll") for (int j = 0; j < 2; ++j)                          \
        gload16(aBase[j] + co_, (void*)&As[DBN_][(H_) >> 1][(j*8 + w)*512]); \
    }                                                                        \
  } while (0)

#define PH(DB_, T_, P_, STG_, DOVM_, VM_) do {                               \
    __builtin_amdgcn_sched_barrier(0);                                       \
    if (STG_) STAGE((T_) + 1, (DB_) ^ 1, P_);                                \
    bf16x8 af_[4];                                                           \
    _Pragma("unroll") for (int mm = 0; mm < 4; ++mm)                         \
      af_[mm] = *(const bf16x8*)                                             \
          &As[DB_][(P_) >> 1][aIdx + (((P_) & 1) * 4 + mm) * 512];           \
    if (((P_) & 1) == 0) {                                                   \
      _Pragma("unroll") for (int nn = 0; nn < 4; ++nn)                       \
        bfr[nn] = *(const bf16x8*)&Bs[DB_][(P_) >> 1][bIdx + nn * 512];      \
    }                                                                        \
    __builtin_amdgcn_s_barrier();                                            \
    __builtin_amdgcn_s_setprio(1);                                           \
    _Pragma("unroll") for (int mm = 0; mm < 4; ++mm)                         \
      _Pragma("unroll") for (int nn = 0; nn < 4; ++nn)                       \
        acc[((P_) & 1) * 4 + mm][nn] =                                       \
            __builtin_amdgcn_mfma_f32_16x16x32_bf16(                         \
                af_[mm], bfr[nn], acc[((P_) & 1) * 4 + mm][nn], 0, 0, 0);    \
    __builtin_amdgcn_s_setprio(0);                                           \
    if (DOVM_) { asm volatile("s_waitcnt vmcnt(" #VM_ ")" ::: "memory"); }   \
    __builtin_amdgcn_s_barrier();                                            \
  } while (0)

  // prologue: stage tile 0's 4 half-tiles, land h0,h1 (leave h2,h3 in flight)
  STAGE(0, 0, 0); STAGE(0, 0, 1); STAGE(0, 0, 2); STAGE(0, 0, 3);
  asm volatile("s_waitcnt vmcnt(4)" ::: "memory");
  __builtin_amdgcn_s_barrier();

  for (int t2 = 0; t2 < 14; t2 += 2) {
    PH(0, t2, 0, 1, 0, 0); PH(0, t2, 1, 1, 1, 4);
    PH(0, t2, 2, 1, 0, 0); PH(0, t2, 3, 1, 1, 4);
    PH(1, t2 + 1, 0, 1, 0, 0); PH(1, t2 + 1, 1, 1, 1, 4);
    PH(1, t2 + 1, 2, 1, 0, 0); PH(1, t2 + 1, 3, 1, 1, 4);
  }
  PH(0, 14, 0, 1, 0, 0); PH(0, 14, 1, 1, 1, 4);
  PH(0, 14, 2, 1, 0, 0); PH(0, 14, 3, 1, 1, 4);
  PH(1, 15, 0, 0, 0, 0); PH(1, 15, 1, 0, 1, 0);
  PH(1, 15, 2, 0, 0, 0); PH(1, 15, 3, 0, 0, 0);

#undef PH
#undef STAGE

  // ---- epilogue: C/D layout col = lane&15 (frame), row = (lane>>4)*4 + j ----
  const int cn = l & 15, rb = (l >> 4) * 4;
  size_t obase[4];
#pragma unroll
  for (int n = 0; n < 4; ++n) {
    const int fg = tileN + wn * 64 + n * 16 + cn;   // < 32768
    const int bb = fg / NFR;
    const int fb = fg - bb * NFR;
    obase[n] = (size_t)bb * M_OUT * NFR + fb;
  }
#pragma unroll
  for (int m = 0; m < 8; ++m) {
    const int o0 = tileM + wm * 128 + m * 16 + rb;  // < 1024
#pragma unroll
    for (int j = 0; j < 4; ++j) {
      const int o = o0 + j;
#pragma unroll
      for (int n = 0; n < 4; ++n)
        out[obase[n] + (size_t)o * NFR] = acc[m][n][j];
    }
  }
}

// ---------------- tail: rows 1024/1025 (all frames) + frames 32768..32775 ----------------
__global__ __launch_bounds__(256) void stft_tail3(
    const float* __restrict__ basis,            // [1026][1024] f32
    const __hip_bfloat16* __restrict__ xp,      // [NB][XP2]
    const __hip_bfloat16* __restrict__ basisBf, // [1024][1024]
    float* __restrict__ out) {
  const int blk = blockIdx.x;
  if (blk < TAIL_ROW) {
    // rows 1024/1025, 32 frames/block, K-split 8x128 + LDS reduce
    __shared__ float b0[1024], b1[1024];
    __shared__ float part[2][8][32];
    for (int i = threadIdx.x; i < 1024; i += 256) {
      b0[i] = basis[1024 * 1024 + i];
      b1[i] = basis[1025 * 1024 + i];
    }
    __syncthreads();
    const int fl = threadIdx.x & 31, ks = threadIdx.x >> 5;
    const int fg = blk * 32 + fl;
    float s0 = 0.f, s1 = 0.f;
    if (fg < NTOT) {
      const int b = fg / NFR, fb = fg - b * NFR;
      const __hip_bfloat16* w = xp + (size_t)b * XP2 + (size_t)fb * HOP + ks * 128;
      const float* bb0 = b0 + ks * 128;
      const float* bb1 = b1 + ks * 128;
#pragma unroll 4
      for (int k = 0; k < 128; k += 8) {
        union { bf16x8 v; unsigned short u[8]; } uu;
        uu.v = *(const bf16x8*)&w[k];
#pragma unroll
        for (int j = 0; j < 8; ++j) {
          const float xv = bf2f(uu.u[j]);
          s0 += bb0[k + j] * xv;
          s1 += bb1[k + j] * xv;
        }
      }
    }
    part[0][ks][fl] = s0;
    part[1][ks][fl] = s1;
    __syncthreads();
    if (threadIdx.x < 64) {
      const int row = threadIdx.x >> 5, f = threadIdx.x & 31;
      const int fg2 = blk * 32 + f;
      if (fg2 < NTOT) {
        float s = 0.f;
#pragma unroll
        for (int k2 = 0; k2 < 8; ++k2) s += part[row][k2][f];
        const int b = fg2 / NFR, fb = fg2 - b * NFR;
        out[((size_t)b * M_OUT + 1024 + row) * NFR + fb] = s;
      }
    }
  } else {
    // frames 32768..32775 (batch 7) x rows 0..1023; block = (frame, 128-row group)
    const int idx = blk - TAIL_ROW;          // 0..63
    const int f8 = idx >> 3, rg = idx & 7;
    const int fb = 4089 + f8;                // fg - 7*NFR
    __shared__ __hip_bfloat16 win[1024];
    const __hip_bfloat16* w = xp + (size_t)7 * XP2 + (size_t)fb * HOP;
    for (int i = threadIdx.x; i < 1024; i += 256) win[i] = w[i];
    __syncthreads();
    const int r = rg * 128 + (threadIdx.x >> 1);
    const int kh = threadIdx.x & 1;
    const __hip_bfloat16* br = basisBf + (size_t)r * FL + kh * 512;
    const __hip_bfloat16* wk = win + kh * 512;
    float s = 0.f;
    for (int k = 0; k < 512; k += 8) {
      union { bf16x8 v; unsigned short u[8]; } ub, ux;
      ub.v = *(const bf16x8*)&br[k];
      ux.v = *(const bf16x8*)&wk[k];
#pragma unroll
      for (int j = 0; j < 8; ++j) s += bf2f(ub.u[j]) * bf2f(ux.u[j]);
    }
    s += __shfl_xor(s, 1);
    if (kh == 0) out[((size_t)7 * M_OUT + r) * NFR + fb] = s;
  }
}

extern "C" void kernel_launch(void* const* d_in, const int* in_sizes, int n_in,
                              void* d_out, int out_size, void* d_ws, size_t ws_size,
                              hipStream_t stream) {
  const float* x = (const float*)d_in[0];       // [8, 1048576] f32
  const float* basis = (const float*)d_in[1];   // [1026, 1, 1024] f32
  float* out = (float*)d_out;                   // [8, 1026, 4097] f32

  __hip_bfloat16* xpBf = (__hip_bfloat16*)d_ws;                 // NB*XP2 bf16
  __hip_bfloat16* basisBf = xpBf + (size_t)NB * XP2;            // 1024*FL bf16

  dim3 gPad((XP2 / 8 + 255) / 256, NB);
  pad_convert_x8<<<gPad, 256, 0, stream>>>(x, xpBf);

  convert_basis8<<<(1024 * FL / 8) / 256, 256, 0, stream>>>(basis, basisBf);

  stft_gemm8<<<NWGM, 512, 0, stream>>>(basisBf, xpBf, out);
  stft_tail3<<<TAIL_BLKS, 256, 0, stream>>>(basis, xpBf, basisBf, out);
}

// Round 6
// 109.878 us; speedup vs baseline: 1.5854x; 1.0118x over previous
//
#include <hip/hip_runtime.h>
#include <hip/hip_bf16.h>

// ---------------- problem constants ----------------
#define T_LEN 1048576
#define FL    1024
#define PADL  512
#define HOP   256
#define NFR   4097            // frames per batch
#define NB    8
#define NTOT  32776           // NB*NFR
#define XP2   1049600         // T_LEN + FL (reflect-padded length per batch)
#define M_OUT 1026
#define BM 256
#define BN 256
#define MT 4                  // 1024 rows
#define NT 128                // 32768 frames in main GEMM
#define NWGM 512              // MT*NT -> exactly 2 rounds at 1 block/CU
#define TAIL_ROW 1025         // ceil(NTOT/32)
#define TAIL_BLKS 1089        // + 64 frame-tail blocks

typedef __bf16 bf16x8 __attribute__((ext_vector_type(8)));
typedef float  f32x4  __attribute__((ext_vector_type(4)));

__device__ __forceinline__ void gload16(const __hip_bfloat16* g, void* l) {
  __builtin_amdgcn_global_load_lds(
      (const __attribute__((address_space(1))) unsigned int*)g,
      (__attribute__((address_space(3))) unsigned int*)l, 16, 0, 0);
}

__device__ __forceinline__ float bf2f(unsigned short h) {
  union { unsigned u; float f; } c; c.u = ((unsigned)h) << 16; return c.f;
}

// ---------------- prep: reflect-pad x, convert to bf16 (8 elems/thread) ----------------
__global__ __launch_bounds__(256) void pad_convert_x8(
    const float* __restrict__ x, __hip_bfloat16* __restrict__ xp) {
  const int base = (blockIdx.x * 256 + threadIdx.x) * 8;
  const int b = blockIdx.y;
  if (base >= XP2) return;
  const float* __restrict__ xb = x + (size_t)b * T_LEN;
  union { bf16x8 v; __hip_bfloat16 h[8]; } o;
  if (base >= PADL && base + 8 <= PADL + T_LEN) {
    const float4 v0 = *(const float4*)&xb[base - PADL];
    const float4 v1 = *(const float4*)&xb[base - PADL + 4];
    o.h[0] = __float2bfloat16(v0.x); o.h[1] = __float2bfloat16(v0.y);
    o.h[2] = __float2bfloat16(v0.z); o.h[3] = __float2bfloat16(v0.w);
    o.h[4] = __float2bfloat16(v1.x); o.h[5] = __float2bfloat16(v1.y);
    o.h[6] = __float2bfloat16(v1.z); o.h[7] = __float2bfloat16(v1.w);
    *(bf16x8*)&xp[(size_t)b * XP2 + base] = o.v;
  } else {
    for (int e = 0; e < 8; ++e) {
      const int i = base + e;
      if (i < XP2) {
        const int t = i - PADL;
        const int idx = (t < 0) ? -t : ((t >= T_LEN) ? (2 * T_LEN - 2 - t) : t);
        xp[(size_t)b * XP2 + i] = __float2bfloat16(xb[idx]);
      }
    }
  }
}

// ---------------- prep: basis rows 0..1023 to bf16 (8 elems/thread) ----------------
__global__ __launch_bounds__(256) void convert_basis8(
    const float* __restrict__ basis, __hip_bfloat16* __restrict__ bb) {
  const int base = (blockIdx.x * 256 + threadIdx.x) * 8;
  if (base >= 1024 * FL) return;
  const float4 v0 = *(const float4*)&basis[base];
  const float4 v1 = *(const float4*)&basis[base + 4];
  union { bf16x8 v; __hip_bfloat16 h[8]; } o;
  o.h[0] = __float2bfloat16(v0.x); o.h[1] = __float2bfloat16(v0.y);
  o.h[2] = __float2bfloat16(v0.z); o.h[3] = __float2bfloat16(v0.w);
  o.h[4] = __float2bfloat16(v1.x); o.h[5] = __float2bfloat16(v1.y);
  o.h[6] = __float2bfloat16(v1.z); o.h[7] = __float2bfloat16(v1.w);
  *(bf16x8*)&bb[base] = o.v;
}

// ---------------- main GEMM: 256x256, reg-double-buffered 4-window schedule ----------------
// BK=64 per tile, 2 K-halves x 2 m-halves = 4 windows/tile. Each window:
// {ds_reads for NEXT window's fragments, 1 half-tile stage, MFMA on PREV
// window's fragments} -> LDS pipe overlaps matrix pipe. 1 barrier/window,
// counted vmcnt(2) at W0/W2. LDS 2 dbuf x 2 kh x [256][32] x {A,B} = 128 KiB.
__global__ __launch_bounds__(512, 2) void stft_gemm8(
    const __hip_bfloat16* __restrict__ A,   // [1024][FL]
    const __hip_bfloat16* __restrict__ X,   // [NB][XP2]
    float* __restrict__ out) {              // [NB][M_OUT][NFR]
  __shared__ __hip_bfloat16 As[2][2][256 * 32];
  __shared__ __hip_bfloat16 Bs[2][2][256 * 32];

  // XCD swizzle (512 % 8 == 0)
  const int orig = blockIdx.x;
  const int wg = (orig & 7) * (NWGM / 8) + (orig >> 3);
  const int mtile = wg & 3, ntile = wg >> 2;
  const int tileM = mtile * BM, tileN = ntile * BN;

  const int tid = threadIdx.x;
  const int w = tid >> 6, l = tid & 63;     // 8 waves
  const int wm = w >> 2, wn = w & 3;        // 2M x 4N; per-wave 128x64

  // ---- staging addressing (pre-swizzled global source, linear LDS dest) ----
  const int g_log = (l & 3) ^ ((l >> 3) & 3);
  const int srow = l >> 2;
  const __hip_bfloat16* aBase[2];
  const __hip_bfloat16* bBase[2];
#pragma unroll
  for (int j = 0; j < 2; ++j) {
    const int c = j * 8 + w;
    aBase[j] = A + (size_t)(tileM + c * 16 + srow) * FL + g_log * 8;
    const int fg = tileN + c * 16 + srow;            // < 32768
    const int bb = fg / NFR;
    const int fb = fg - bb * NFR;
    bBase[j] = X + (size_t)bb * XP2 + (size_t)fb * HOP + g_log * 8;
  }

  // ---- fragment read addressing (swizzled; 2-way bank alias = free) ----
  const int swz = ((l >> 4) ^ ((l >> 1) & 3)) * 8;
  const int aIdx = (wm * 128 + (l & 15)) * 32 + swz;
  const int bIdx = (wn * 64 + (l & 15)) * 32 + swz;

  f32x4 acc[8][4] = {};
  bf16x8 afA[4], afB[4], bfr0[4], bfr1[4];

#define STAGE_H(TT_, DBN_, H_) do {                                          \
    const int co_ = (TT_) * 64 + ((H_) >> 1) * 32;                           \
    if ((H_) & 1) {                                                          \
      _Pragma("unroll") for (int j = 0; j < 2; ++j)                          \
        gload16(bBase[j] + co_, (void*)&Bs[DBN_][(H_) >> 1][(j*8 + w)*512]); \
    } else {                                                                 \
      _Pragma("unroll") for (int j = 0; j < 2; ++j)                          \
        gload16(aBase[j] + co_, (void*)&As[DBN_][(H_) >> 1][(j*8 + w)*512]); \
    }                                                                        \
  } while (0)

#define RD_A(dst_, DB_, KH_, MH_) do {                                       \
    _Pragma("unroll") for (int mm = 0; mm < 4; ++mm)                         \
      dst_[mm] = *(const bf16x8*)&As[DB_][KH_][aIdx + ((MH_)*4 + mm)*512];   \
  } while (0)

#define RD_B(dst_, DB_, KH_) do {                                            \
    _Pragma("unroll") for (int nn = 0; nn < 4; ++nn)                         \
      dst_[nn] = *(const bf16x8*)&Bs[DB_][KH_][bIdx + nn*512];               \
  } while (0)

#define MM(afx_, bfx_, MH_) do {                                             \
    __builtin_amdgcn_s_setprio(1);                                           \
    _Pragma("unroll") for (int mm = 0; mm < 4; ++mm)                         \
      _Pragma("unroll") for (int nn = 0; nn < 4; ++nn)                       \
        acc[(MH_)*4 + mm][nn] = __builtin_amdgcn_mfma_f32_16x16x32_bf16(     \
            afx_[mm], bfx_[nn], acc[(MH_)*4 + mm][nn], 0, 0, 0);             \
    __builtin_amdgcn_s_setprio(0);                                           \
  } while (0)

#define VM2 asm volatile("s_waitcnt vmcnt(2)" ::: "memory")
#define BAR __builtin_amdgcn_s_barrier()
#define SB  __builtin_amdgcn_sched_barrier(0)

  // TILE(T_, DB_): DB_ must be a literal 0/1
#define TILE(T_, DB_) do {                                                   \
    /* W0: MFMA(mh0,kh0) uses afA,bfr0 (read last window) */                 \
    SB; STAGE_H((T_) + 1, (DB_) ^ 1, 0);                                     \
    RD_A(afB, DB_, 0, 1);                                                    \
    MM(afA, bfr0, 0);                                                        \
    VM2; BAR;                                                                \
    /* W1: MFMA(mh1,kh0) */                                                  \
    SB; STAGE_H((T_) + 1, (DB_) ^ 1, 1);                                     \
    RD_A(afA, DB_, 1, 0); RD_B(bfr1, DB_, 1);                                \
    MM(afB, bfr0, 1);                                                        \
    BAR;                                                                     \
    /* W2: MFMA(mh0,kh1) */                                                  \
    SB; STAGE_H((T_) + 1, (DB_) ^ 1, 2);                                     \
    RD_A(afB, DB_, 1, 1);                                                    \
    MM(afA, bfr1, 0);                                                        \
    VM2; BAR;                                                                \
    /* W3: MFMA(mh1,kh1); prefetch next tile's kh0 fragments */              \
    SB; STAGE_H((T_) + 1, (DB_) ^ 1, 3);                                     \
    RD_A(afA, (DB_) ^ 1, 0, 0); RD_B(bfr0, (DB_) ^ 1, 0);                    \
    MM(afB, bfr1, 1);                                                        \
    BAR;                                                                     \
  } while (0)

  // prologue: stage tile 0 fully, land kh0 halves, pre-read W0 fragments
  STAGE_H(0, 0, 0); STAGE_H(0, 0, 1); STAGE_H(0, 0, 2); STAGE_H(0, 0, 3);
  asm volatile("s_waitcnt vmcnt(4)" ::: "memory");
  BAR;
  RD_A(afA, 0, 0, 0); RD_B(bfr0, 0, 0);

  for (int tt = 0; tt < 7; ++tt) {
    TILE(2 * tt, 0);
    TILE(2 * tt + 1, 1);
  }
  TILE(14, 0);

  // peeled tile 15 (DB=1): no stages, drain remaining loads at W0
  SB;
  RD_A(afB, 1, 0, 1);
  MM(afA, bfr0, 0);
  asm volatile("s_waitcnt vmcnt(0)" ::: "memory");
  BAR;
  SB;
  RD_A(afA, 1, 1, 0); RD_B(bfr1, 1, 1);
  MM(afB, bfr0, 1);
  RD_A(afB, 1, 1, 1);
  MM(afA, bfr1, 0);
  MM(afB, bfr1, 1);

#undef TILE
#undef VM2
#undef BAR
#undef SB
#undef MM
#undef RD_B
#undef RD_A
#undef STAGE_H

  // ---- epilogue: C/D layout col = lane&15 (frame), row = (lane>>4)*4 + j ----
  const int cn = l & 15, rb = (l >> 4) * 4;
  size_t obase[4];
#pragma unroll
  for (int n = 0; n < 4; ++n) {
    const int fg = tileN + wn * 64 + n * 16 + cn;   // < 32768
    const int bb = fg / NFR;
    const int fb = fg - bb * NFR;
    obase[n] = (size_t)bb * M_OUT * NFR + fb;
  }
#pragma unroll
  for (int m = 0; m < 8; ++m) {
    const int o0 = tileM + wm * 128 + m * 16 + rb;  // < 1024
#pragma unroll
    for (int j = 0; j < 4; ++j) {
      const int o = o0 + j;
#pragma unroll
      for (int n = 0; n < 4; ++n)
        out[obase[n] + (size_t)o * NFR] = acc[m][n][j];
    }
  }
}

// ---------------- tail: rows 1024/1025 (all frames) + frames 32768..32775 ----------------
__global__ __launch_bounds__(256) void stft_tail3(
    const float* __restrict__ basis,            // [1026][1024] f32
    const __hip_bfloat16* __restrict__ xp,      // [NB][XP2]
    const __hip_bfloat16* __restrict__ basisBf, // [1024][1024]
    float* __restrict__ out) {
  const int blk = blockIdx.x;
  if (blk < TAIL_ROW) {
    // rows 1024/1025, 32 frames/block, K-split 8x128 + LDS reduce
    __shared__ float b0[1024], b1[1024];
    __shared__ float part[2][8][32];
    for (int i = threadIdx.x; i < 1024; i += 256) {
      b0[i] = basis[1024 * 1024 + i];
      b1[i] = basis[1025 * 1024 + i];
    }
    __syncthreads();
    const int fl = threadIdx.x & 31, ks = threadIdx.x >> 5;
    const int fg = blk * 32 + fl;
    float s0 = 0.f, s1 = 0.f;
    if (fg < NTOT) {
      const int b = fg / NFR, fb = fg - b * NFR;
      const __hip_bfloat16* w = xp + (size_t)b * XP2 + (size_t)fb * HOP + ks * 128;
      const float* bb0 = b0 + ks * 128;
      const float* bb1 = b1 + ks * 128;
#pragma unroll 4
      for (int k = 0; k < 128; k += 8) {
        union { bf16x8 v; unsigned short u[8]; } uu;
        uu.v = *(const bf16x8*)&w[k];
#pragma unroll
        for (int j = 0; j < 8; ++j) {
          const float xv = bf2f(uu.u[j]);
          s0 += bb0[k + j] * xv;
          s1 += bb1[k + j] * xv;
        }
      }
    }
    part[0][ks][fl] = s0;
    part[1][ks][fl] = s1;
    __syncthreads();
    if (threadIdx.x < 64) {
      const int row = threadIdx.x >> 5, f = threadIdx.x & 31;
      const int fg2 = blk * 32 + f;
      if (fg2 < NTOT) {
        float s = 0.f;
#pragma unroll
        for (int k2 = 0; k2 < 8; ++k2) s += part[row][k2][f];
        const int b = fg2 / NFR, fb = fg2 - b * NFR;
        out[((size_t)b * M_OUT + 1024 + row) * NFR + fb] = s;
      }
    }
  } else {
    // frames 32768..32775 (batch 7) x rows 0..1023; block = (frame, 128-row group)
    const int idx = blk - TAIL_ROW;          // 0..63
    const int f8 = idx >> 3, rg = idx & 7;
    const int fb = 4089 + f8;                // fg - 7*NFR
    __shared__ __hip_bfloat16 win[1024];
    const __hip_bfloat16* w = xp + (size_t)7 * XP2 + (size_t)fb * HOP;
    for (int i = threadIdx.x; i < 1024; i += 256) win[i] = w[i];
    __syncthreads();
    const int r = rg * 128 + (threadIdx.x >> 1);
    const int kh = threadIdx.x & 1;
    const __hip_bfloat16* br = basisBf + (size_t)r * FL + kh * 512;
    const __hip_bfloat16* wk = win + kh * 512;
    float s = 0.f;
    for (int k = 0; k < 512; k += 8) {
      union { bf16x8 v; unsigned short u[8]; } ub, ux;
      ub.v = *(const bf16x8*)&br[k];
      ux.v = *(const bf16x8*)&wk[k];
#pragma unroll
      for (int j = 0; j < 8; ++j) s += bf2f(ub.u[j]) * bf2f(ux.u[j]);
    }
    s += __shfl_xor(s, 1);
    if (kh == 0) out[((size_t)7 * M_OUT + r) * NFR + fb] = s;
  }
}

extern "C" void kernel_launch(void* const* d_in, const int* in_sizes, int n_in,
                              void* d_out, int out_size, void* d_ws, size_t ws_size,
                              hipStream_t stream) {
  const float* x = (const float*)d_in[0];       // [8, 1048576] f32
  const float* basis = (const float*)d_in[1];   // [1026, 1, 1024] f32
  float* out = (float*)d_out;                   // [8, 1026, 4097] f32

  __hip_bfloat16* xpBf = (__hip_bfloat16*)d_ws;                 // NB*XP2 bf16
  __hip_bfloat16* basisBf = xpBf + (size_t)NB * XP2;            // 1024*FL bf16

  dim3 gPad((XP2 / 8 + 255) / 256, NB);
  pad_convert_x8<<<gPad, 256, 0, stream>>>(x, xpBf);

  convert_basis8<<<(1024 * FL / 8) / 256, 256, 0, stream>>>(basis, basisBf);

  stft_gemm8<<<NWGM, 512, 0, stream>>>(basisBf, xpBf, out);
  stft_tail3<<<TAIL_BLKS, 256, 0, stream>>>(basis, xpBf, basisBf, out);
}

// Round 7
// 109.246 us; speedup vs baseline: 1.5946x; 1.0058x over previous
//
#include <hip/hip_runtime.h>
#include <hip/hip_bf16.h>

// ---------------- problem constants ----------------
#define T_LEN 1048576
#define FL    1024
#define PADL  512
#define HOP   256
#define NFR   4097            // frames per batch
#define NB    8
#define NTOT  32776           // NB*NFR
#define XP2   1049600         // T_LEN + FL (reflect-padded length per batch)
#define M_OUT 1026
#define BM 256
#define BN 256
#define MT 4                  // 1024 rows
#define NT 128                // 32768 frames in main GEMM
#define NWGM 512              // MT*NT -> exactly 2 rounds at 1 block/CU
#define TAIL_ROW 1025         // ceil(NTOT/32)
#define TAIL_BLKS 1089        // + 64 frame-tail blocks

typedef __bf16 bf16x8 __attribute__((ext_vector_type(8)));
typedef float  f32x4  __attribute__((ext_vector_type(4)));

__device__ __forceinline__ void gload16(const __hip_bfloat16* g, void* l) {
  __builtin_amdgcn_global_load_lds(
      (const __attribute__((address_space(1))) unsigned int*)g,
      (__attribute__((address_space(3))) unsigned int*)l, 16, 0, 0);
}

__device__ __forceinline__ float bf2f(unsigned short h) {
  union { unsigned u; float f; } c; c.u = ((unsigned)h) << 16; return c.f;
}

// ---------------- prep: reflect-pad x, convert to bf16 (8 elems/thread) ----------------
__global__ __launch_bounds__(256) void pad_convert_x8(
    const float* __restrict__ x, __hip_bfloat16* __restrict__ xp) {
  const int base = (blockIdx.x * 256 + threadIdx.x) * 8;
  const int b = blockIdx.y;
  if (base >= XP2) return;
  const float* __restrict__ xb = x + (size_t)b * T_LEN;
  union { bf16x8 v; __hip_bfloat16 h[8]; } o;
  if (base >= PADL && base + 8 <= PADL + T_LEN) {
    const float4 v0 = *(const float4*)&xb[base - PADL];
    const float4 v1 = *(const float4*)&xb[base - PADL + 4];
    o.h[0] = __float2bfloat16(v0.x); o.h[1] = __float2bfloat16(v0.y);
    o.h[2] = __float2bfloat16(v0.z); o.h[3] = __float2bfloat16(v0.w);
    o.h[4] = __float2bfloat16(v1.x); o.h[5] = __float2bfloat16(v1.y);
    o.h[6] = __float2bfloat16(v1.z); o.h[7] = __float2bfloat16(v1.w);
    *(bf16x8*)&xp[(size_t)b * XP2 + base] = o.v;
  } else {
    for (int e = 0; e < 8; ++e) {
      const int i = base + e;
      if (i < XP2) {
        const int t = i - PADL;
        const int idx = (t < 0) ? -t : ((t >= T_LEN) ? (2 * T_LEN - 2 - t) : t);
        xp[(size_t)b * XP2 + i] = __float2bfloat16(xb[idx]);
      }
    }
  }
}

// ---------------- prep: basis rows 0..1023 to bf16 (8 elems/thread) ----------------
__global__ __launch_bounds__(256) void convert_basis8(
    const float* __restrict__ basis, __hip_bfloat16* __restrict__ bb) {
  const int base = (blockIdx.x * 256 + threadIdx.x) * 8;
  if (base >= 1024 * FL) return;
  const float4 v0 = *(const float4*)&basis[base];
  const float4 v1 = *(const float4*)&basis[base + 4];
  union { bf16x8 v; __hip_bfloat16 h[8]; } o;
  o.h[0] = __float2bfloat16(v0.x); o.h[1] = __float2bfloat16(v0.y);
  o.h[2] = __float2bfloat16(v0.z); o.h[3] = __float2bfloat16(v0.w);
  o.h[4] = __float2bfloat16(v1.x); o.h[5] = __float2bfloat16(v1.y);
  o.h[6] = __float2bfloat16(v1.z); o.h[7] = __float2bfloat16(v1.w);
  *(bf16x8*)&bb[base] = o.v;
}

// ---------------- main GEMM: 256x256, BK=32, 4-slot deep pipeline ----------------
// 32 k-tiles; per tile 2 windows (m-half). Stage LEAD-3 (tile T stages T+3),
// ONE vmcnt(4) + ONE s_barrier per tile (load issue->wait gap = 3+ windows).
// No intra-tile barriers: waves skew, LDS pipe overlaps matrix pipe.
// Reg double-buffered fragments. LDS: 4 slots x [256][32] x {A,B} = 128 KiB.
__global__ __launch_bounds__(512, 2) void stft_gemm8(
    const __hip_bfloat16* __restrict__ A,   // [1024][FL]
    const __hip_bfloat16* __restrict__ X,   // [NB][XP2]
    float* __restrict__ out) {              // [NB][M_OUT][NFR]
  __shared__ __hip_bfloat16 As[4][256 * 32];
  __shared__ __hip_bfloat16 Bs[4][256 * 32];

  // XCD swizzle (512 % 8 == 0)
  const int orig = blockIdx.x;
  const int wg = (orig & 7) * (NWGM / 8) + (orig >> 3);
  const int mtile = wg & 3, ntile = wg >> 2;
  const int tileM = mtile * BM, tileN = ntile * BN;

  const int tid = threadIdx.x;
  const int w = tid >> 6, l = tid & 63;     // 8 waves
  const int wm = w >> 2, wn = w & 3;        // 2M x 4N; per-wave 128x64

  // ---- staging addressing (pre-swizzled global source, linear LDS dest) ----
  const int g_log = (l & 3) ^ ((l >> 3) & 3);
  const int srow = l >> 2;
  const __hip_bfloat16* aBase[2];
  const __hip_bfloat16* bBase[2];
#pragma unroll
  for (int j = 0; j < 2; ++j) {
    const int c = j * 8 + w;
    aBase[j] = A + (size_t)(tileM + c * 16 + srow) * FL + g_log * 8;
    const int fg = tileN + c * 16 + srow;            // < 32768
    const int bb = fg / NFR;
    const int fb = fg - bb * NFR;
    bBase[j] = X + (size_t)bb * XP2 + (size_t)fb * HOP + g_log * 8;
  }

  // ---- fragment read addressing (swizzled; 2-way bank alias = free) ----
  const int swz = ((l >> 4) ^ ((l >> 1) & 3)) * 8;
  const int aIdx = (wm * 128 + (l & 15)) * 32 + swz;
  const int bIdx = (wn * 64 + (l & 15)) * 32 + swz;

  f32x4 acc[8][4] = {};
  bf16x8 afA[4], afB[4], bfrE[4], bfrO[4];

#define STAGE_A(KO_, SL_) do {                                               \
    _Pragma("unroll") for (int j = 0; j < 2; ++j)                            \
      gload16(aBase[j] + (KO_), (void*)&As[SL_][(j*8 + w)*512]);             \
  } while (0)

#define STAGE_B(KO_, SL_) do {                                               \
    _Pragma("unroll") for (int j = 0; j < 2; ++j)                            \
      gload16(bBase[j] + (KO_), (void*)&Bs[SL_][(j*8 + w)*512]);             \
  } while (0)

#define RD_A(dst_, SL_, MH_) do {                                            \
    _Pragma("unroll") for (int mm = 0; mm < 4; ++mm)                         \
      dst_[mm] = *(const bf16x8*)&As[SL_][aIdx + ((MH_)*4 + mm)*512];        \
  } while (0)

#define RD_B(dst_, SL_) do {                                                 \
    _Pragma("unroll") for (int nn = 0; nn < 4; ++nn)                         \
      dst_[nn] = *(const bf16x8*)&Bs[SL_][bIdx + nn*512];                    \
  } while (0)

#define MM(afx_, bfx_, MH_) do {                                             \
    __builtin_amdgcn_s_setprio(1);                                           \
    _Pragma("unroll") for (int mm = 0; mm < 4; ++mm)                         \
      _Pragma("unroll") for (int nn = 0; nn < 4; ++nn)                       \
        acc[(MH_)*4 + mm][nn] = __builtin_amdgcn_mfma_f32_16x16x32_bf16(     \
            afx_[mm], bfx_[nn], acc[(MH_)*4 + mm][nn], 0, 0, 0);             \
    __builtin_amdgcn_s_setprio(0);                                           \
  } while (0)

#define BAR __builtin_amdgcn_s_barrier()
#define SB  __builtin_amdgcn_sched_barrier(0)

  // TILE: S_=this slot, NS_=next slot, SS_=stage slot, KO_=stage k-offset,
  // BFC_/BFN_ = this/next tile's B-frag set, DOSTG_, DOVM_, VMN_ (literal)
#define TILE(S_, NS_, SS_, KO_, BFC_, BFN_, DOSTG_, DOVM_, VMN_) do {        \
    /* W0 (m-half 0) */                                                      \
    SB;                                                                      \
    if (DOSTG_) STAGE_A(KO_, SS_);                                           \
    RD_A(afB, S_, 1);                                                        \
    MM(afA, BFC_, 0);                                                        \
    /* W1 (m-half 1) + next-tile fragment pre-reads */                       \
    SB;                                                                      \
    if (DOSTG_) STAGE_B(KO_, SS_);                                           \
    RD_A(afA, NS_, 0);                                                       \
    RD_B(BFN_, NS_);                                                         \
    MM(afB, BFC_, 1);                                                        \
    if (DOVM_) { asm volatile("s_waitcnt vmcnt(" #VMN_ ")" ::: "memory"); }  \
    BAR;                                                                     \
  } while (0)

  // prologue: stage tiles 0,1,2; land tile 0; pre-read its W0 fragments
  STAGE_A(0, 0);   STAGE_B(0, 0);
  STAGE_A(32, 1);  STAGE_B(32, 1);
  STAGE_A(64, 2);  STAGE_B(64, 2);
  asm volatile("s_waitcnt vmcnt(8)" ::: "memory");
  BAR;
  RD_A(afA, 0, 0); RD_B(bfrE, 0);

  for (int q = 0; q < 7; ++q) {             // tiles 4q..4q+3  (T = 0..27)
    const int ko = (4 * q + 3) * 32;        // stage k-offset for T+3
    TILE(0, 1, 3, ko,      bfrE, bfrO, 1, 1, 4);
    TILE(1, 2, 0, ko + 32, bfrO, bfrE, 1, 1, 4);
    TILE(2, 3, 1, ko + 64, bfrE, bfrO, 1, 1, 4);
    TILE(3, 0, 2, ko + 96, bfrO, bfrE, 1, 1, 4);
  }
  // T=28 (slot 0, even): stages tile 31 -> slot 3
  TILE(0, 1, 3, 31 * 32, bfrE, bfrO, 1, 1, 4);
  // T=29 (slot 1, odd): no stage; full drain (tile 31 must land)
  TILE(1, 2, 0, 0, bfrO, bfrE, 0, 1, 0);
  // T=30 (slot 2, even): no stage, no vmcnt
  TILE(2, 3, 1, 0, bfrE, bfrO, 0, 0, 0);
  // T=31 (slot 3, odd): peeled, no next-tile reads
  SB;
  RD_A(afB, 3, 1);
  MM(afA, bfrO, 0);
  MM(afB, bfrO, 1);

#undef TILE
#undef BAR
#undef SB
#undef MM
#undef RD_B
#undef RD_A
#undef STAGE_B
#undef STAGE_A

  // ---- epilogue: C/D layout col = lane&15 (frame), row = (lane>>4)*4 + j ----
  const int cn = l & 15, rb = (l >> 4) * 4;
  size_t obase[4];
#pragma unroll
  for (int n = 0; n < 4; ++n) {
    const int fg = tileN + wn * 64 + n * 16 + cn;   // < 32768
    const int bb = fg / NFR;
    const int fb = fg - bb * NFR;
    obase[n] = (size_t)bb * M_OUT * NFR + fb;
  }
#pragma unroll
  for (int m = 0; m < 8; ++m) {
    const int o0 = tileM + wm * 128 + m * 16 + rb;  // < 1024
#pragma unroll
    for (int j = 0; j < 4; ++j) {
      const int o = o0 + j;
#pragma unroll
      for (int n = 0; n < 4; ++n)
        out[obase[n] + (size_t)o * NFR] = acc[m][n][j];
    }
  }
}

// ---------------- tail: rows 1024/1025 (all frames) + frames 32768..32775 ----------------
__global__ __launch_bounds__(256) void stft_tail3(
    const float* __restrict__ basis,            // [1026][1024] f32
    const __hip_bfloat16* __restrict__ xp,      // [NB][XP2]
    const __hip_bfloat16* __restrict__ basisBf, // [1024][1024]
    float* __restrict__ out) {
  const int blk = blockIdx.x;
  if (blk < TAIL_ROW) {
    // rows 1024/1025, 32 frames/block, K-split 8x128 + LDS reduce
    __shared__ float b0[1024], b1[1024];
    __shared__ float part[2][8][32];
    for (int i = threadIdx.x; i < 1024; i += 256) {
      b0[i] = basis[1024 * 1024 + i];
      b1[i] = basis[1025 * 1024 + i];
    }
    __syncthreads();
    const int fl = threadIdx.x & 31, ks = threadIdx.x >> 5;
    const int fg = blk * 32 + fl;
    float s0 = 0.f, s1 = 0.f;
    if (fg < NTOT) {
      const int b = fg / NFR, fb = fg - b * NFR;
      const __hip_bfloat16* w = xp + (size_t)b * XP2 + (size_t)fb * HOP + ks * 128;
      const float* bb0 = b0 + ks * 128;
      const float* bb1 = b1 + ks * 128;
#pragma unroll 4
      for (int k = 0; k < 128; k += 8) {
        union { bf16x8 v; unsigned short u[8]; } uu;
        uu.v = *(const bf16x8*)&w[k];
#pragma unroll
        for (int j = 0; j < 8; ++j) {
          const float xv = bf2f(uu.u[j]);
          s0 += bb0[k + j] * xv;
          s1 += bb1[k + j] * xv;
        }
      }
    }
    part[0][ks][fl] = s0;
    part[1][ks][fl] = s1;
    __syncthreads();
    if (threadIdx.x < 64) {
      const int row = threadIdx.x >> 5, f = threadIdx.x & 31;
      const int fg2 = blk * 32 + f;
      if (fg2 < NTOT) {
        float s = 0.f;
#pragma unroll
        for (int k2 = 0; k2 < 8; ++k2) s += part[row][k2][f];
        const int b = fg2 / NFR, fb = fg2 - b * NFR;
        out[((size_t)b * M_OUT + 1024 + row) * NFR + fb] = s;
      }
    }
  } else {
    // frames 32768..32775 (batch 7) x rows 0..1023; block = (frame, 128-row group)
    const int idx = blk - TAIL_ROW;          // 0..63
    const int f8 = idx >> 3, rg = idx & 7;
    const int fb = 4089 + f8;                // fg - 7*NFR
    __shared__ __hip_bfloat16 win[1024];
    const __hip_bfloat16* w = xp + (size_t)7 * XP2 + (size_t)fb * HOP;
    for (int i = threadIdx.x; i < 1024; i += 256) win[i] = w[i];
    __syncthreads();
    const int r = rg * 128 + (threadIdx.x >> 1);
    const int kh = threadIdx.x & 1;
    const __hip_bfloat16* br = basisBf + (size_t)r * FL + kh * 512;
    const __hip_bfloat16* wk = win + kh * 512;
    float s = 0.f;
    for (int k = 0; k < 512; k += 8) {
      union { bf16x8 v; unsigned short u[8]; } ub, ux;
      ub.v = *(const bf16x8*)&br[k];
      ux.v = *(const bf16x8*)&wk[k];
#pragma unroll
      for (int j = 0; j < 8; ++j) s += bf2f(ub.u[j]) * bf2f(ux.u[j]);
    }
    s += __shfl_xor(s, 1);
    if (kh == 0) out[((size_t)7 * M_OUT + r) * NFR + fb] = s;
  }
}

extern "C" void kernel_launch(void* const* d_in, const int* in_sizes, int n_in,
                              void* d_out, int out_size, void* d_ws, size_t ws_size,
                              hipStream_t stream) {
  const float* x = (const float*)d_in[0];       // [8, 1048576] f32
  const float* basis = (const float*)d_in[1];   // [1026, 1, 1024] f32
  float* out = (float*)d_out;                   // [8, 1026, 4097] f32

  __hip_bfloat16* xpBf = (__hip_bfloat16*)d_ws;                 // NB*XP2 bf16
  __hip_bfloat16* basisBf = xpBf + (size_t)NB * XP2;            // 1024*FL bf16

  dim3 gPad((XP2 / 8 + 255) / 256, NB);
  pad_convert_x8<<<gPad, 256, 0, stream>>>(x, xpBf);

  convert_basis8<<<(1024 * FL / 8) / 256, 256, 0, stream>>>(basis, basisBf);

  stft_gemm8<<<NWGM, 512, 0, stream>>>(basisBf, xpBf, out);
  stft_tail3<<<TAIL_BLKS, 256, 0, stream>>>(basis, xpBf, basisBf, out);
}